// Round 1
// 338.283 us; speedup vs baseline: 1.0041x; 1.0041x over previous
//
#include <hip/hip_runtime.h>

typedef unsigned short u16;
typedef short bf16x8 __attribute__((ext_vector_type(8)));
typedef float f32x4 __attribute__((ext_vector_type(4)));

#define NF 65536
#define GCH 512      // number of 128-frame chunks

__device__ __forceinline__ float sigm(float x){ return 1.0f/(1.0f+__expf(-x)); }

__device__ __forceinline__ u16 f2bf(float f){
  union { float f; unsigned u; } v; v.f = f;
  unsigned r = (v.u + 0x7fffu + ((v.u >> 16) & 1u)) >> 16;   // RNE
  return (u16)r;
}

#define AS1(p) ((const __attribute__((address_space(1))) unsigned int*)(p))
#define AS3(p) ((__attribute__((address_space(3))) unsigned int*)(p))

// ---------------- prep: pack W1, W2 into MFMA fragment-ready bf16 layouts.
__global__ __launch_bounds__(256) void k_prep(const float* __restrict__ W1, const float* __restrict__ W2,
                                              u16* __restrict__ W1f, u16* __restrict__ W2f){
  int idx = blockIdx.x*256 + threadIdx.x;     // 0..131071
  {
    int j  = idx & 7;
    int L  = (idx >> 3) & 63;
    int ks = (idx >> 9) & 1;
    int rt = (idx >> 10) & 15;
    int ck = idx >> 14;
    int row = 16*rt + (L & 15);
    int k   = ck*64 + ks*32 + ((L >> 4) << 3) + j;
    W1f[idx] = f2bf(W1[row*512 + k]);
  }
  if (idx < 32768){
    int j  = idx & 7;
    int L  = (idx >> 3) & 63;
    int ks = (idx >> 9) & 3;
    int rt = idx >> 11;
    int row = 16*rt + (L & 15);
    int m   = ks*32 + ((L >> 4) << 3) + j;
    W2f[idx] = f2bf(W2[row*128 + m]);
  }
}

// ---------------- transpose+convert: x (512, 65536) fp32 -> xT (65536, 512) bf16
__global__ __launch_bounds__(256) void k_tr(const float* __restrict__ x, u16* __restrict__ xT){
  __shared__ float ls[64*65];                  // stride 65: 2-way max bank aliasing
  const int tid = threadIdx.x;
  const int bt = blockIdx.x & 1023, bk = blockIdx.x >> 10;   // 1024 x 8 tiles
  const int T0 = bt*64, K0 = bk*64;
  #pragma unroll
  for (int l=0;l<4;l++){
    int idx = tid + l*256;                     // 0..1023 float4s
    int kl = idx >> 4, c4 = idx & 15;
    float4 v = *(const float4*)(x + (size_t)(K0+kl)*NF + T0 + c4*4);
    float* d = ls + kl*65 + c4*4;
    d[0]=v.x; d[1]=v.y; d[2]=v.z; d[3]=v.w;
  }
  __syncthreads();
  #pragma unroll
  for (int l=0;l<2;l++){
    int p = tid + l*256;                       // 0..511 packs of 8
    int t = p >> 3, kb = p & 7;
    unsigned u[8];
    #pragma unroll
    for (int m=0;m<8;m++) u[m] = f2bf(ls[(kb*8+m)*65 + t]);
    uint4 pk;
    pk.x = u[0] | (u[1]<<16); pk.y = u[2] | (u[3]<<16);
    pk.z = u[4] | (u[5]<<16); pk.w = u[6] | (u[7]<<16);
    *(uint4*)(xT + (size_t)(T0+t)*512 + K0 + kb*8) = pk;
  }
}

// ---------------- GEMM1 (MFMA bf16) + fused chunk-reduce (replaces k_red)
// 256 rows x 128 frames per block, K=512. Block g == chunk g.
__global__ __launch_bounds__(256, 2) void k_gemm1(const u16* __restrict__ xT,
        const u16* __restrict__ W1f, const float* __restrict__ B1,
        float* __restrict__ Aa, float* __restrict__ Bb,
        float* __restrict__ Ac, float* __restrict__ Bc){
  __shared__ __align__(16) u16 ws[16384];      // 32 KB: [rt][ks][lane][8]
  __shared__ __align__(16) u16 xs[8192];       // 16 KB: [c][ks][lane][8]
  const int tid = threadIdx.x;
  const int wv = tid >> 6, L = tid & 63;
  const int q = L >> 4, ln = L & 15;
  const int g = blockIdx.x;
  const int F0 = g * 128;
  const int rt0 = 2*wv;

  f32x4 acc[4][8];
  #pragma unroll
  for (int a=0;a<4;a++)
    #pragma unroll
    for (int c=0;c<8;c++) acc[a][c] = (f32x4){0.f,0.f,0.f,0.f};

  for (int ck=0; ck<8; ++ck){
    #pragma unroll
    for (int i=0;i<8;i++){
      int s = wv*8 + i;
      __builtin_amdgcn_global_load_lds(AS1(W1f + ck*16384 + s*512 + L*8), AS3(ws + s*512), 16, 0, 0);
    }
    #pragma unroll
    for (int i=0;i<4;i++){
      int s = wv*4 + i;
      int c = s >> 1, ks = s & 1;
      int t = F0 + c*16 + ln;
      int k = ck*64 + ks*32 + q*8;
      __builtin_amdgcn_global_load_lds(AS1(xT + (size_t)t*512 + k), AS3(xs + s*512), 16, 0, 0);
    }
    __syncthreads();
    #pragma unroll
    for (int ks=0; ks<2; ++ks){
      bf16x8 af[4];
      af[0] = ((const bf16x8*)ws)[( rt0   *2+ks)*64 + L];
      af[1] = ((const bf16x8*)ws)[((rt0+1)*2+ks)*64 + L];
      af[2] = ((const bf16x8*)ws)[((rt0+8)*2+ks)*64 + L];
      af[3] = ((const bf16x8*)ws)[((rt0+9)*2+ks)*64 + L];
      #pragma unroll
      for (int c=0;c<8;c++){
        bf16x8 bf = ((const bf16x8*)xs)[(c*2+ks)*64 + L];
        acc[0][c] = __builtin_amdgcn_mfma_f32_16x16x32_bf16(af[0], bf, acc[0][c], 0,0,0);
        acc[1][c] = __builtin_amdgcn_mfma_f32_16x16x32_bf16(af[1], bf, acc[1][c], 0,0,0);
        acc[2][c] = __builtin_amdgcn_mfma_f32_16x16x32_bf16(af[2], bf, acc[2][c], 0,0,0);
        acc[3][c] = __builtin_amdgcn_mfma_f32_16x16x32_bf16(af[3], bf, acc[3][c], 0,0,0);
      }
    }
    __syncthreads();
  }
  // epilogue: sigmoid, a = le*ri, b = 1-le; store Aa/Bb AND compose the
  // chunk-total affine map per channel (order-preserving: shfl tree over the
  // 16 contiguous frames per c-tile, then sequential across c).
  #pragma unroll
  for (int pr=0; pr<2; ++pr){
    int mb = 32*wv + 16*pr + 4*q;              // row base in 0..124
    float bl[4], br[4];
    #pragma unroll
    for (int r=0;r<4;r++){ bl[r] = B1[mb+r]; br[r] = B1[mb+128+r]; }
    float RA[4], RB[4];
    #pragma unroll
    for (int c=0;c<8;c++){
      int t = F0 + 16*c + ln;
      f32x4 Lv = acc[pr][c], Rv = acc[pr+2][c];
      float a4[4], b4[4];
      #pragma unroll
      for (int r=0;r<4;r++){
        float le = sigm(Lv[r] + bl[r]);
        float ri = sigm(Rv[r] + br[r]);
        a4[r] = le*ri; b4[r] = 1.0f - le;
      }
      *(float4*)(Aa + (size_t)t*128 + mb) = make_float4(a4[0],a4[1],a4[2],a4[3]);
      *(float4*)(Bb + (size_t)t*128 + mb) = make_float4(b4[0],b4[1],b4[2],b4[3]);
      #pragma unroll
      for (int r=0;r<4;r++){
        float As = a4[r], Bs = b4[r];
        #pragma unroll
        for (int d=1; d<16; d<<=1){
          float Ap = __shfl_xor(As, d);
          float Bp = __shfl_xor(Bs, d);
          // lower-ln half is the EARLIER t-range: B = A_later*B_early + B_later
          Bs = (ln & d) ? fmaf(As, Bp, Bs) : fmaf(Ap, Bs, Bp);
          As *= Ap;
        }
        if (c == 0){ RA[r] = As; RB[r] = Bs; }
        else       { RB[r] = fmaf(As, RB[r], Bs); RA[r] *= As; }
      }
    }
    if (ln == 0){
      #pragma unroll
      for (int r=0;r<4;r++){
        Ac[g*128 + mb + r] = RA[r];
        Bc[g*128 + mb + r] = RB[r];
      }
    }
  }
}

// ---------------- chunk-carry exclusive scan: 8-way segmented, 1 block
__global__ __launch_bounds__(1024) void k_scan(const float* __restrict__ Ac, const float* __restrict__ Bc,
                                               float* __restrict__ Pb){
  __shared__ float sA[8][128], sB[8][128];
  const int tid = threadIdx.x;
  const int m = tid & 127, s = tid >> 7;      // 8 segments x 64 chunks
  const int g0 = s*64;
  float A = 1.f, B = 0.f;
  #pragma unroll 16
  for (int i=0;i<64;i++){
    float a = Ac[(g0+i)*128 + m], b = Bc[(g0+i)*128 + m];
    B = fmaf(a, B, b);
    A *= a;
  }
  sA[s][m] = A; sB[s][m] = B;
  __syncthreads();
  float v = 0.f;                               // value entering segment start
  for (int s2=0; s2<s; ++s2) v = fmaf(sA[s2][m], v, sB[s2][m]);
  #pragma unroll 16
  for (int i=0;i<64;i++){
    int g = g0+i;
    Pb[g*128+m] = v;                           // exclusive prefix before chunk g
    v = fmaf(Ac[g*128+m], v, Bc[g*128+m]);
  }
}

// ---------------- apply: parallel z-recompute (512 thr, 4 segs/channel) + MFMA GEMM2
__global__ __launch_bounds__(512, 2) void k_apply(const float* __restrict__ Aa, const float* __restrict__ Bb,
        const float* __restrict__ Pb, const u16* __restrict__ W2f, const float* __restrict__ B2,
        float* __restrict__ out){
  __shared__ __align__(16) u16 zf[16384];      // 32 KB
  __shared__ float sA[4][128], sB[4][128];     // 4 KB seg carries
  const int tid = threadIdx.x;
  const int g = blockIdx.x, T0 = g*128;

  // phase 1: all 512 threads; thread (m, s4) owns frames [32*s4, 32*s4+32)
  {
    const int m = tid & 127, s4 = tid >> 7;
    const float* ap = Aa + (size_t)(T0 + s4*32)*128 + m;
    const float* bp = Bb + (size_t)(T0 + s4*32)*128 + m;
    float areg[32], breg[32];
    #pragma unroll
    for (int i=0;i<32;i++){ areg[i] = ap[(size_t)i*128]; breg[i] = bp[(size_t)i*128]; }
    float A = 1.f, Bv = 0.f;
    #pragma unroll
    for (int i=0;i<32;i++){ Bv = fmaf(areg[i], Bv, breg[i]); A *= areg[i]; }
    sA[s4][m] = A; sB[s4][m] = Bv;
    __syncthreads();
    float v = Pb[g*128 + m];                   // value entering the chunk
    for (int s2=0; s2<s4; ++s2) v = fmaf(sA[s2][m], v, sB[s2][m]);
    const int base_m = (m>>5)*512 + ((m>>3)&3)*128 + (m&7);
    #pragma unroll
    for (int i=0;i<32;i++){
      int t = s4*32 + i;
      zf[base_m + (t>>4)*2048 + (t&15)*8] = f2bf(v);
      v = fmaf(areg[i], v, breg[i]);
    }
  }
  __syncthreads();

  const int wv = tid >> 6, L = tid & 63;
  const int q = L >> 4, ln = L & 15;
  f32x4 acc[2][8];
  #pragma unroll
  for (int a=0;a<2;a++)
    #pragma unroll
    for (int c=0;c<8;c++) acc[a][c] = (f32x4){0.f,0.f,0.f,0.f};

  #pragma unroll
  for (int ks=0; ks<4; ++ks){
    bf16x8 af0 = ((const bf16x8*)W2f)[((2*wv  )*4+ks)*64 + L];   // L2-hot, 64 KB
    bf16x8 af1 = ((const bf16x8*)W2f)[((2*wv+1)*4+ks)*64 + L];
    #pragma unroll
    for (int c=0;c<8;c++){
      bf16x8 bf = ((const bf16x8*)zf)[(c*4+ks)*64 + L];
      acc[0][c] = __builtin_amdgcn_mfma_f32_16x16x32_bf16(af0, bf, acc[0][c], 0,0,0);
      acc[1][c] = __builtin_amdgcn_mfma_f32_16x16x32_bf16(af1, bf, acc[1][c], 0,0,0);
    }
  }

  #pragma unroll
  for (int rs=0;rs<2;rs++){
    int rowb = (2*wv+rs)*16 + q*4;
    float b2[4];
    #pragma unroll
    for (int r=0;r<4;r++) b2[r] = B2[rowb+r];
    #pragma unroll
    for (int c=0;c<8;c++){
      int t = T0 + 16*c + ln;
      #pragma unroll
      for (int r=0;r<4;r++)
        out[(size_t)(rowb+r)*NF + t] = sigm(-(acc[rs][c][r] + b2[r]));  // 1-sigmoid(y)=sigmoid(-y)
    }
  }
}

extern "C" void kernel_launch(void* const* d_in, const int* in_sizes, int n_in,
                              void* d_out, int out_size, void* d_ws, size_t ws_size,
                              hipStream_t stream) {
  const float* x  = (const float*)d_in[0];   // (512, 65536)
  const float* W1 = (const float*)d_in[1];   // (256, 512)
  const float* B1 = (const float*)d_in[2];   // (256, 1)
  const float* W2 = (const float*)d_in[3];   // (256, 128)
  const float* B2 = (const float*)d_in[4];   // (256, 1)
  float* out = (float*)d_out;                // (256, 65536) = 64 MB

  u16*   W1f = (u16*)d_ws;                   // 131072 u16
  u16*   W2f = W1f + 131072;                 // 32768 u16
  float* Aa  = (float*)d_ws + 81920;         // 65536*128 fp32
  float* Bb  = Aa + (size_t)NF*128;
  float* Ac  = Bb + (size_t)NF*128;
  float* Bc  = Ac + (size_t)GCH*128;
  float* Pb  = Bc + (size_t)GCH*128;
  u16*   xT  = (u16*)d_out;                  // 64 MB, dead before k_apply writes out

  k_prep <<<512, 256, 0, stream>>>(W1, W2, W1f, W2f);
  k_tr   <<<8192, 256, 0, stream>>>(x, xT);
  k_gemm1<<<512, 256, 0, stream>>>(xT, W1f, B1, Aa, Bb, Ac, Bc);
  k_scan <<<1, 1024, 0, stream>>>(Ac, Bc, Pb);
  k_apply<<<GCH, 512, 0, stream>>>(Aa, Bb, Pb, W2f, B2, out);
}

// Round 2
// 299.394 us; speedup vs baseline: 1.1346x; 1.1299x over previous
//
#include <hip/hip_runtime.h>

typedef unsigned short u16;
typedef short bf16x8 __attribute__((ext_vector_type(8)));
typedef float f32x4 __attribute__((ext_vector_type(4)));

#define NF 65536
#define GCH 512      // number of 128-frame chunks

__device__ __forceinline__ float sigm(float x){ return 1.0f/(1.0f+__expf(-x)); }

__device__ __forceinline__ u16 f2bf(float f){
  union { float f; unsigned u; } v; v.f = f;
  unsigned r = (v.u + 0x7fffu + ((v.u >> 16) & 1u)) >> 16;   // RNE
  return (u16)r;
}

#define AS1(p) ((const __attribute__((address_space(1))) unsigned int*)(p))
#define AS3(p) ((__attribute__((address_space(3))) unsigned int*)(p))

// ---------------- prep: pack W1, W2 into MFMA fragment-ready bf16 layouts.
__global__ __launch_bounds__(256) void k_prep(const float* __restrict__ W1, const float* __restrict__ W2,
                                              u16* __restrict__ W1f, u16* __restrict__ W2f){
  int idx = blockIdx.x*256 + threadIdx.x;     // 0..131071
  {
    int j  = idx & 7;
    int L  = (idx >> 3) & 63;
    int ks = (idx >> 9) & 1;
    int rt = (idx >> 10) & 15;
    int ck = idx >> 14;
    int row = 16*rt + (L & 15);
    int k   = ck*64 + ks*32 + ((L >> 4) << 3) + j;
    W1f[idx] = f2bf(W1[row*512 + k]);
  }
  if (idx < 32768){
    int j  = idx & 7;
    int L  = (idx >> 3) & 63;
    int ks = (idx >> 9) & 3;
    int rt = idx >> 11;
    int row = 16*rt + (L & 15);
    int m   = ks*32 + ((L >> 4) << 3) + j;
    W2f[idx] = f2bf(W2[row*128 + m]);
  }
}

// ---------------- GEMM1 (MFMA bf16) with FUSED transpose+convert of x, plus
// fused chunk-reduce. 256 rows x 128 frames per block, K=512. Block g == chunk g.
// Per ck: stage x fp32 rows into ls (linear, global_load_lds), W1 frags direct
// from L2 into regs; transpose-convert ls -> xs (bf16 frag layout); MFMA.
__global__ __launch_bounds__(256, 2) void k_gemm1(const float* __restrict__ x,
        const u16* __restrict__ W1f, const float* __restrict__ B1,
        float* __restrict__ Aa, float* __restrict__ Bb,
        float* __restrict__ Ac, float* __restrict__ Bc){
  __shared__ __align__(16) float ls[8192];     // 32 KB: x chunk fp32 [64 k][128 t]
  __shared__ __align__(16) u16  xs[8192];      // 16 KB: [c][ks][lane][8] bf16 frags
  const int tid = threadIdx.x;
  const int wv = tid >> 6, L = tid & 63;
  const int q = L >> 4, ln = L & 15;
  const int g = blockIdx.x;
  const int F0 = g * 128;
  const int rt0 = 2*wv;
  const bf16x8* W1f8 = (const bf16x8*)W1f;

  f32x4 acc[4][8];
  #pragma unroll
  for (int a=0;a<4;a++)
    #pragma unroll
    for (int c=0;c<8;c++) acc[a][c] = (f32x4){0.f,0.f,0.f,0.f};

  for (int ck=0; ck<8; ++ck){
    // stage x rows [ck*64, ck*64+64) x cols [F0, F0+128) -> ls, linear
    #pragma unroll
    for (int i=0;i<8;i++){
      int seg = wv*8 + i;                      // 0..31, 1 KB each (2 rows)
      __builtin_amdgcn_global_load_lds(
        AS1(x + (size_t)(ck*64 + seg*2 + (L>>5))*NF + F0 + (L&31)*4),
        AS3(ls + seg*256), 16, 0, 0);
    }
    // W1 fragments straight from L2 (W1f is 256 KB, hot)
    bf16x8 af[2][4];
    #pragma unroll
    for (int ks=0;ks<2;ks++){
      af[ks][0] = W1f8[ck*2048 + ((rt0  )*2+ks)*64 + L];
      af[ks][1] = W1f8[ck*2048 + ((rt0+1)*2+ks)*64 + L];
      af[ks][2] = W1f8[ck*2048 + ((rt0+8)*2+ks)*64 + L];
      af[ks][3] = W1f8[ck*2048 + ((rt0+9)*2+ks)*64 + L];
    }
    __syncthreads();                           // ls staged (also fences prev MFMA's xs reads)
    // transpose-convert: each thread emits 4 frag-slots (8 elems = 1 uint4)
    // slot bits: [3:0]=ln [4]=codd [6:5]=q [8:7]=chi [9]=ks ; c = 2*chi+codd
    // wave-instr bank pattern: (codd*16+ln) -> 32 banks, 2-way max (free)
    #pragma unroll
    for (int i=0;i<4;i++){
      int s    = tid + 256*i;
      int lns  = s & 15;
      int codd = (s >> 4) & 1;
      int qs   = (s >> 5) & 3;
      int chi  = (s >> 7) & 3;
      int kss  = (s >> 9) & 1;
      int cc   = chi*2 + codd;
      const float* rp = ls + (kss*32 + qs*8)*128 + cc*16 + lns;
      unsigned u[8];
      #pragma unroll
      for (int j=0;j<8;j++) u[j] = f2bf(rp[j*128]);
      uint4 pk;
      pk.x = u[0] | (u[1]<<16); pk.y = u[2] | (u[3]<<16);
      pk.z = u[4] | (u[5]<<16); pk.w = u[6] | (u[7]<<16);
      *(uint4*)(xs + ((cc*2+kss)*64 + qs*16 + lns)*8) = pk;
    }
    __syncthreads();                           // xs ready; ls reads done
    #pragma unroll
    for (int ks=0; ks<2; ++ks){
      #pragma unroll
      for (int c=0;c<8;c++){
        bf16x8 bf = ((const bf16x8*)xs)[(c*2+ks)*64 + L];
        acc[0][c] = __builtin_amdgcn_mfma_f32_16x16x32_bf16(af[ks][0], bf, acc[0][c], 0,0,0);
        acc[1][c] = __builtin_amdgcn_mfma_f32_16x16x32_bf16(af[ks][1], bf, acc[1][c], 0,0,0);
        acc[2][c] = __builtin_amdgcn_mfma_f32_16x16x32_bf16(af[ks][2], bf, acc[2][c], 0,0,0);
        acc[3][c] = __builtin_amdgcn_mfma_f32_16x16x32_bf16(af[ks][3], bf, acc[3][c], 0,0,0);
      }
    }
    // no barrier needed: next stage writes ls only; MFMA reads xs/regs only
  }
  __syncthreads();
  // epilogue: sigmoid, a = le*ri, b = 1-le; store Aa/Bb AND compose the
  // chunk-total affine map per channel (shfl tree over 16 frames, then across c)
  #pragma unroll
  for (int pr=0; pr<2; ++pr){
    int mb = 32*wv + 16*pr + 4*q;              // row base in 0..124
    float bl[4], br[4];
    #pragma unroll
    for (int r=0;r<4;r++){ bl[r] = B1[mb+r]; br[r] = B1[mb+128+r]; }
    float RA[4], RB[4];
    #pragma unroll
    for (int c=0;c<8;c++){
      int t = F0 + 16*c + ln;
      f32x4 Lv = acc[pr][c], Rv = acc[pr+2][c];
      float a4[4], b4[4];
      #pragma unroll
      for (int r=0;r<4;r++){
        float le = sigm(Lv[r] + bl[r]);
        float ri = sigm(Rv[r] + br[r]);
        a4[r] = le*ri; b4[r] = 1.0f - le;
      }
      *(float4*)(Aa + (size_t)t*128 + mb) = make_float4(a4[0],a4[1],a4[2],a4[3]);
      *(float4*)(Bb + (size_t)t*128 + mb) = make_float4(b4[0],b4[1],b4[2],b4[3]);
      #pragma unroll
      for (int r=0;r<4;r++){
        float As = a4[r], Bs = b4[r];
        #pragma unroll
        for (int d=1; d<16; d<<=1){
          float Ap = __shfl_xor(As, d);
          float Bp = __shfl_xor(Bs, d);
          Bs = (ln & d) ? fmaf(As, Bp, Bs) : fmaf(Ap, Bs, Bp);
          As *= Ap;
        }
        if (c == 0){ RA[r] = As; RB[r] = Bs; }
        else       { RB[r] = fmaf(As, RB[r], Bs); RA[r] *= As; }
      }
    }
    if (ln == 0){
      #pragma unroll
      for (int r=0;r<4;r++){
        Ac[g*128 + mb + r] = RA[r];
        Bc[g*128 + mb + r] = RB[r];
      }
    }
  }
}

// ---------------- apply: redundant per-block chunk-prefix scan (replaces k_scan)
// + parallel z-recompute (512 thr, 4 segs/channel) + MFMA GEMM2
__global__ __launch_bounds__(512, 2) void k_apply(const float* __restrict__ Aa, const float* __restrict__ Bb,
        const float* __restrict__ Ac, const float* __restrict__ Bc,
        const u16* __restrict__ W2f, const float* __restrict__ B2,
        float* __restrict__ out){
  __shared__ __align__(16) u16 zf[16384];      // 32 KB
  __shared__ float sA[4][128], sB[4][128];     // 4 KB seg carries (reused by both phases)
  const int tid = threadIdx.x;
  const int g = blockIdx.x, T0 = g*128;
  const int m = tid & 127, s4 = tid >> 7;

  // phase 0: this block's own exclusive prefix over chunks [0, g)
  float vpref;
  {
    int c0 = s4*128, c1 = c0 + 128; if (c1 > g) c1 = g;
    float A = 1.f, B = 0.f;
    #pragma unroll 4
    for (int c = c0; c < c1; ++c){
      float a = Ac[c*128 + m], b = Bc[c*128 + m];
      B = fmaf(a, B, b);
      A *= a;
    }
    sA[s4][m] = A; sB[s4][m] = B;              // empty segment -> identity (1,0)
    __syncthreads();
    float v = 0.f;
    #pragma unroll
    for (int s2=0; s2<4; ++s2) v = fmaf(sA[s2][m], v, sB[s2][m]);
    vpref = v;
    __syncthreads();                           // before sA/sB reuse
  }

  // phase 1: thread (m, s4) owns frames [32*s4, 32*s4+32) of this chunk
  {
    const float* ap = Aa + (size_t)(T0 + s4*32)*128 + m;
    const float* bp = Bb + (size_t)(T0 + s4*32)*128 + m;
    float areg[32], breg[32];
    #pragma unroll
    for (int i=0;i<32;i++){ areg[i] = ap[(size_t)i*128]; breg[i] = bp[(size_t)i*128]; }
    float A = 1.f, Bv = 0.f;
    #pragma unroll
    for (int i=0;i<32;i++){ Bv = fmaf(areg[i], Bv, breg[i]); A *= areg[i]; }
    sA[s4][m] = A; sB[s4][m] = Bv;
    __syncthreads();
    float v = vpref;                           // value entering the chunk
    for (int s2=0; s2<s4; ++s2) v = fmaf(sA[s2][m], v, sB[s2][m]);
    const int base_m = (m>>5)*512 + ((m>>3)&3)*128 + (m&7);
    #pragma unroll
    for (int i=0;i<32;i++){
      int t = s4*32 + i;
      zf[base_m + (t>>4)*2048 + (t&15)*8] = f2bf(v);
      v = fmaf(areg[i], v, breg[i]);
    }
  }
  __syncthreads();

  const int wv = tid >> 6, L = tid & 63;
  const int q = L >> 4, ln = L & 15;
  f32x4 acc[2][8];
  #pragma unroll
  for (int a=0;a<2;a++)
    #pragma unroll
    for (int c=0;c<8;c++) acc[a][c] = (f32x4){0.f,0.f,0.f,0.f};

  #pragma unroll
  for (int ks=0; ks<4; ++ks){
    bf16x8 af0 = ((const bf16x8*)W2f)[((2*wv  )*4+ks)*64 + L];   // L2-hot, 64 KB
    bf16x8 af1 = ((const bf16x8*)W2f)[((2*wv+1)*4+ks)*64 + L];
    #pragma unroll
    for (int c=0;c<8;c++){
      bf16x8 bf = ((const bf16x8*)zf)[(c*4+ks)*64 + L];
      acc[0][c] = __builtin_amdgcn_mfma_f32_16x16x32_bf16(af0, bf, acc[0][c], 0,0,0);
      acc[1][c] = __builtin_amdgcn_mfma_f32_16x16x32_bf16(af1, bf, acc[1][c], 0,0,0);
    }
  }

  #pragma unroll
  for (int rs=0;rs<2;rs++){
    int rowb = (2*wv+rs)*16 + q*4;
    float b2[4];
    #pragma unroll
    for (int r=0;r<4;r++) b2[r] = B2[rowb+r];
    #pragma unroll
    for (int c=0;c<8;c++){
      int t = T0 + 16*c + ln;
      #pragma unroll
      for (int r=0;r<4;r++)
        out[(size_t)(rowb+r)*NF + t] = sigm(-(acc[rs][c][r] + b2[r]));  // 1-sigmoid(y)=sigmoid(-y)
    }
  }
}

extern "C" void kernel_launch(void* const* d_in, const int* in_sizes, int n_in,
                              void* d_out, int out_size, void* d_ws, size_t ws_size,
                              hipStream_t stream) {
  const float* x  = (const float*)d_in[0];   // (512, 65536)
  const float* W1 = (const float*)d_in[1];   // (256, 512)
  const float* B1 = (const float*)d_in[2];   // (256, 1)
  const float* W2 = (const float*)d_in[3];   // (256, 128)
  const float* B2 = (const float*)d_in[4];   // (256, 1)
  float* out = (float*)d_out;                // (256, 65536) = 64 MB

  u16*   W1f = (u16*)d_ws;                   // 131072 u16
  u16*   W2f = W1f + 131072;                 // 32768 u16
  float* Aa  = (float*)d_ws + 81920;         // 65536*128 fp32
  float* Bb  = Aa + (size_t)NF*128;
  float* Ac  = Bb + (size_t)NF*128;
  float* Bc  = Ac + (size_t)GCH*128;

  k_prep <<<512, 256, 0, stream>>>(W1, W2, W1f, W2f);
  k_gemm1<<<512, 256, 0, stream>>>(x, W1f, B1, Aa, Bb, Ac, Bc);
  k_apply<<<GCH, 512, 0, stream>>>(Aa, Bb, Ac, Bc, W2f, B2, out);
}

// Round 5
// 287.202 us; speedup vs baseline: 1.1827x; 1.0424x over previous
//
#include <hip/hip_runtime.h>

typedef unsigned short u16;
typedef short bf16x8 __attribute__((ext_vector_type(8)));
typedef float f32x4 __attribute__((ext_vector_type(4)));

#define NF 65536
#define NSC 1024     // sub-chunks of 64 frames
#define NMAC 16      // macros of 64 sub-chunks

__device__ __forceinline__ float sigm(float x){ return 1.0f/(1.0f+__expf(-x)); }

__device__ __forceinline__ u16 f2bf(float f){
  union { float f; unsigned u; } v; v.f = f;
  unsigned r = (v.u + 0x7fffu + ((v.u >> 16) & 1u)) >> 16;   // RNE
  return (u16)r;
}

#define AS1(p) ((const __attribute__((address_space(1))) unsigned int*)(p))
#define AS3(p) ((__attribute__((address_space(3))) unsigned int*)(p))

// ---------------- prep: pack W1, W2 into MFMA fragment-ready bf16 layouts.
__global__ __launch_bounds__(256) void k_prep(const float* __restrict__ W1, const float* __restrict__ W2,
                                              u16* __restrict__ W1f, u16* __restrict__ W2f){
  int idx = blockIdx.x*256 + threadIdx.x;     // 0..131071
  {
    int j  = idx & 7;
    int L  = (idx >> 3) & 63;
    int ks = (idx >> 9) & 1;
    int rt = (idx >> 10) & 15;
    int ck = idx >> 14;
    int row = 16*rt + (L & 15);
    int k   = ck*64 + ks*32 + ((L >> 4) << 3) + j;
    W1f[idx] = f2bf(W1[row*512 + k]);
  }
  if (idx < 32768){
    int j  = idx & 7;
    int L  = (idx >> 3) & 63;
    int ks = (idx >> 9) & 3;
    int rt = idx >> 11;
    int row = 16*rt + (L & 15);
    int m   = ks*32 + ((L >> 4) << 3) + j;
    W2f[idx] = f2bf(W2[row*128 + m]);
  }
}

// ---------------- GEMM1: 256 rows x 64 frames per block, K=512, grid 1024.
// __syncthreads-only schedule (hang-proof). Double-buffered x staging with
// issue-early (stage(ck+1) overlaps transpose(ck)); W1f frags from L2;
// fused transpose+convert in LDS; fused sub-chunk affine reduce.
__global__ __launch_bounds__(256, 4) void k_gemm1(const float* __restrict__ x,
        const u16* __restrict__ W1f, const float* __restrict__ B1,
        float* __restrict__ Aa, float* __restrict__ Bb,
        float* __restrict__ Ac, float* __restrict__ Bc){
  __shared__ __align__(16) float ls[8192];     // 2 x 16 KB: x chunk fp32 [64 k][64 t]
  __shared__ __align__(16) u16  xs[4096];      // 8 KB: [c 0..3][ks 0..1][lane][8]
  const int tid = threadIdx.x;
  const int wv = tid >> 6, L = tid & 63;
  const int q = L >> 4, ln = L & 15;
  const int g = blockIdx.x;                    // sub-chunk id
  const int F0 = g * 64;
  const int rt0 = 2*wv;
  const bf16x8* W1f8 = (const bf16x8*)W1f;

  f32x4 acc[4][4];
  #pragma unroll
  for (int a=0;a<4;a++)
    #pragma unroll
    for (int c=0;c<4;c++) acc[a][c] = (f32x4){0.f,0.f,0.f,0.f};

  // prologue: stage ck=0 -> buf0 (16 KB, 4 x 1 KB per wave; dest wave-uniform)
  #pragma unroll
  for (int i=0;i<4;i++){
    int seg = wv*4 + i;
    __builtin_amdgcn_global_load_lds(
      AS1(x + (size_t)(seg*4 + q)*NF + F0 + ln*4),
      AS3(ls + seg*256), 16, 0, 0);
  }

  for (int ck=0; ck<8; ++ck){
    __syncthreads();                           // stage(ck) landed (vmcnt+lgkm drain)
    // issue next stage into the OTHER buffer; overlaps transpose below.
    // WAR safe: that buffer was last read by transpose(ck-1), which completed
    // before barrier2(ck-1) — two barriers ago.
    if (ck < 7){
      #pragma unroll
      for (int i=0;i<4;i++){
        int seg = wv*4 + i;
        __builtin_amdgcn_global_load_lds(
          AS1(x + (size_t)((ck+1)*64 + seg*4 + q)*NF + F0 + ln*4),
          AS3(ls + ((ck+1)&1)*4096 + seg*256), 16, 0, 0);
      }
    }
    // W1 fragments straight from L2 (W1f is 256 KB, hot); consumed after barrier2
    bf16x8 af[2][4];
    #pragma unroll
    for (int ks=0;ks<2;ks++){
      af[ks][0] = W1f8[ck*2048 + ((rt0  )*2+ks)*64 + L];
      af[ks][1] = W1f8[ck*2048 + ((rt0+1)*2+ks)*64 + L];
      af[ks][2] = W1f8[ck*2048 + ((rt0+8)*2+ks)*64 + L];
      af[ks][3] = W1f8[ck*2048 + ((rt0+9)*2+ks)*64 + L];
    }
    // transpose-convert ls[ck&1] -> xs; 2 slots/thread, 8 elems each
    // slot bits: [3:0]=lns [5:4]=cc [7:6]=qs [8]=kss ; banks 2-way max (free)
    {
      const float* lsb = ls + (ck&1)*4096;
      #pragma unroll
      for (int i=0;i<2;i++){
        int s    = tid + 256*i;
        int lns  = s & 15;
        int cc   = (s >> 4) & 3;
        int qs   = (s >> 6) & 3;
        int kss  = (s >> 8) & 1;
        const float* rp = lsb + (kss*32 + qs*8)*64 + cc*16 + lns;
        unsigned u[8];
        #pragma unroll
        for (int j=0;j<8;j++) u[j] = f2bf(rp[j*64]);
        uint4 pk;
        pk.x = u[0] | (u[1]<<16); pk.y = u[2] | (u[3]<<16);
        pk.z = u[4] | (u[5]<<16); pk.w = u[6] | (u[7]<<16);
        *(uint4*)(xs + ((cc*2+kss)*64 + qs*16 + lns)*8) = pk;
      }
    }
    __syncthreads();                           // xs ready (drains stage(ck+1) too)
    #pragma unroll
    for (int ks=0; ks<2; ++ks){
      #pragma unroll
      for (int c=0;c<4;c++){
        bf16x8 bf = ((const bf16x8*)xs)[(c*2+ks)*64 + L];
        acc[0][c] = __builtin_amdgcn_mfma_f32_16x16x32_bf16(af[ks][0], bf, acc[0][c], 0,0,0);
        acc[1][c] = __builtin_amdgcn_mfma_f32_16x16x32_bf16(af[ks][1], bf, acc[1][c], 0,0,0);
        acc[2][c] = __builtin_amdgcn_mfma_f32_16x16x32_bf16(af[ks][2], bf, acc[2][c], 0,0,0);
        acc[3][c] = __builtin_amdgcn_mfma_f32_16x16x32_bf16(af[ks][3], bf, acc[3][c], 0,0,0);
      }
    }
  }

  // epilogue: sigmoid, a = le*ri, b = 1-le; c-outer/pr-inner store order so each
  // 128-B line of Aa/Bb is covered back-to-back; fused sub-chunk affine reduce
  // via 16-lane shfl tree then sequential across c.
  float bl[2][4], br[2][4], RA[2][4], RB[2][4];
  #pragma unroll
  for (int pr=0;pr<2;pr++){
    int mb = 32*wv + 16*pr + 4*q;
    #pragma unroll
    for (int r=0;r<4;r++){ bl[pr][r] = B1[mb+r]; br[pr][r] = B1[mb+128+r]; }
  }
  #pragma unroll
  for (int c=0;c<4;c++){
    int t = F0 + 16*c + ln;
    #pragma unroll
    for (int pr=0;pr<2;pr++){
      int mb = 32*wv + 16*pr + 4*q;
      f32x4 Lv = acc[pr][c], Rv = acc[pr+2][c];
      float a4[4], b4[4];
      #pragma unroll
      for (int r=0;r<4;r++){
        float le = sigm(Lv[r] + bl[pr][r]);
        float ri = sigm(Rv[r] + br[pr][r]);
        a4[r] = le*ri; b4[r] = 1.0f - le;
      }
      *(float4*)(Aa + (size_t)t*128 + mb) = make_float4(a4[0],a4[1],a4[2],a4[3]);
      *(float4*)(Bb + (size_t)t*128 + mb) = make_float4(b4[0],b4[1],b4[2],b4[3]);
      #pragma unroll
      for (int r=0;r<4;r++){
        float As = a4[r], Bs = b4[r];
        #pragma unroll
        for (int d=1; d<16; d<<=1){
          float Ap = __shfl_xor(As, d);
          float Bp = __shfl_xor(Bs, d);
          Bs = (ln & d) ? fmaf(As, Bp, Bs) : fmaf(Ap, Bs, Bp);
          As *= Ap;
        }
        if (c == 0){ RA[pr][r] = As; RB[pr][r] = Bs; }
        else       { RB[pr][r] = fmaf(As, RB[pr][r], Bs); RA[pr][r] *= As; }
      }
    }
  }
  if (ln == 0){
    #pragma unroll
    for (int pr=0;pr<2;pr++){
      int mb = 32*wv + 16*pr + 4*q;
      #pragma unroll
      for (int r=0;r<4;r++){
        Ac[g*128 + mb + r] = RA[pr][r];
        Bc[g*128 + mb + r] = RB[pr][r];
      }
    }
  }
}

// ---------------- macro totals: 16 blocks, each composes 64 sub-chunks
__global__ __launch_bounds__(256) void k_scan(const float* __restrict__ Ac, const float* __restrict__ Bc,
                                              float* __restrict__ MtA, float* __restrict__ MtB){
  __shared__ float sA[2][128], sB[2][128];
  const int j = blockIdx.x;
  const int m = threadIdx.x & 127, s4 = threadIdx.x >> 7;
  const int c0 = j*64 + s4*32;
  float A = 1.f, B = 0.f;
  #pragma unroll 8
  for (int i=0;i<32;i++){
    float a = Ac[(c0+i)*128 + m], b = Bc[(c0+i)*128 + m];
    B = fmaf(a, B, b);
    A *= a;
  }
  sA[s4][m] = A; sB[s4][m] = B;
  __syncthreads();
  if (s4 == 0){
    MtA[j*128+m] = sA[1][m] * sA[0][m];
    MtB[j*128+m] = fmaf(sA[1][m], sB[0][m], sB[1][m]);
  }
}

// ---------------- apply: 64 frames per block, grid 1024.
// phase 0: macro-prefix (<=15 L2-hot steps) + in-macro scan (<=32 steps, 2 segs)
// phase 1: z recompute (2 segs x 32 frames) into zf; then MFMA GEMM2 + epilogue
__global__ __launch_bounds__(256, 4) void k_apply(const float* __restrict__ Aa, const float* __restrict__ Bb,
        const float* __restrict__ Ac, const float* __restrict__ Bc,
        const float* __restrict__ MtA, const float* __restrict__ MtB,
        const u16* __restrict__ W2f, const float* __restrict__ B2,
        float* __restrict__ out){
  __shared__ __align__(16) u16 zf[8192];       // 16 KB: [c 0..3][ks 0..3][lane][8]
  __shared__ float sA[2][128], sB[2][128];
  const int tid = threadIdx.x;
  const int g = blockIdx.x, T0 = g*64;
  const int m = tid & 127, s4 = tid >> 7;

  // phase 0: value entering sub-chunk g
  float vg;
  {
    const int j = g >> 6, r0 = j << 6, n = g & 63;
    int c0 = r0 + s4*32, c1 = r0 + n; if (c1 > c0+32) c1 = c0+32;
    float A = 1.f, B = 0.f;
    for (int c = c0; c < c1; ++c){
      float a = Ac[c*128 + m], b = Bc[c*128 + m];
      B = fmaf(a, B, b);
      A *= a;
    }
    sA[s4][m] = A; sB[s4][m] = B;              // empty segment = identity
    float v = 0.f;
    for (int jj=0; jj<j; ++jj) v = fmaf(MtA[jj*128+m], v, MtB[jj*128+m]);
    __syncthreads();
    v = fmaf(sA[0][m], v, sB[0][m]);
    v = fmaf(sA[1][m], v, sB[1][m]);
    vg = v;
    __syncthreads();                           // before sA/sB reuse
  }

  // phase 1: thread (m, s4) owns frames [32*s4, 32*s4+32) of this sub-chunk
  {
    const float* ap = Aa + (size_t)(T0 + s4*32)*128 + m;
    const float* bp = Bb + (size_t)(T0 + s4*32)*128 + m;
    float areg[32], breg[32];
    #pragma unroll
    for (int i=0;i<32;i++){ areg[i] = ap[(size_t)i*128]; breg[i] = bp[(size_t)i*128]; }
    float A = 1.f, Bv = 0.f;
    #pragma unroll
    for (int i=0;i<32;i++){ Bv = fmaf(areg[i], Bv, breg[i]); A *= areg[i]; }
    sA[s4][m] = A; sB[s4][m] = Bv;
    __syncthreads();
    float v = vg;
    if (s4 == 1) v = fmaf(sA[0][m], v, sB[0][m]);
    const int base_m = (m>>5)*512 + ((m>>3)&3)*128 + (m&7);
    #pragma unroll
    for (int i=0;i<32;i++){
      int t = s4*32 + i;
      zf[base_m + (t>>4)*2048 + (t&15)*8] = f2bf(v);
      v = fmaf(areg[i], v, breg[i]);
    }
  }
  __syncthreads();

  // GEMM2: 4 waves x 4 row-tiles each x 4 c-tiles, K=128
  const int wv = tid >> 6, L = tid & 63;
  const int q = L >> 4, ln = L & 15;
  f32x4 acc[4][4];
  #pragma unroll
  for (int a=0;a<4;a++)
    #pragma unroll
    for (int c=0;c<4;c++) acc[a][c] = (f32x4){0.f,0.f,0.f,0.f};

  #pragma unroll
  for (int ks=0; ks<4; ++ks){
    bf16x8 af[4];
    #pragma unroll
    for (int a=0;a<4;a++) af[a] = ((const bf16x8*)W2f)[((4*wv+a)*4+ks)*64 + L]; // L2-hot
    #pragma unroll
    for (int c=0;c<4;c++){
      bf16x8 bf = ((const bf16x8*)zf)[(c*4+ks)*64 + L];
      #pragma unroll
      for (int a=0;a<4;a++)
        acc[a][c] = __builtin_amdgcn_mfma_f32_16x16x32_bf16(af[a], bf, acc[a][c], 0,0,0);
    }
  }

  #pragma unroll
  for (int a=0;a<4;a++){
    int rowb = (4*wv+a)*16 + q*4;
    float b2[4];
    #pragma unroll
    for (int r=0;r<4;r++) b2[r] = B2[rowb+r];
    #pragma unroll
    for (int r=0;r<4;r++){
      #pragma unroll
      for (int c=0;c<4;c++)
        out[(size_t)(rowb+r)*NF + T0 + 16*c + ln] = sigm(-(acc[a][c][r] + b2[r]));
    }
  }
}

extern "C" void kernel_launch(void* const* d_in, const int* in_sizes, int n_in,
                              void* d_out, int out_size, void* d_ws, size_t ws_size,
                              hipStream_t stream) {
  const float* x  = (const float*)d_in[0];   // (512, 65536)
  const float* W1 = (const float*)d_in[1];   // (256, 512)
  const float* B1 = (const float*)d_in[2];   // (256, 1)
  const float* W2 = (const float*)d_in[3];   // (256, 128)
  const float* B2 = (const float*)d_in[4];   // (256, 1)
  float* out = (float*)d_out;                // (256, 65536) = 64 MB

  u16*   W1f = (u16*)d_ws;                   // 131072 u16
  u16*   W2f = W1f + 131072;                 // 32768 u16
  float* Aa  = (float*)d_ws + 81920;         // 65536*128 fp32
  float* Bb  = Aa + (size_t)NF*128;
  float* Ac  = Bb + (size_t)NF*128;          // 1024*128
  float* Bc  = Ac + (size_t)NSC*128;
  float* MtA = Bc + (size_t)NSC*128;         // 16*128
  float* MtB = MtA + (size_t)NMAC*128;

  k_prep <<<512, 256, 0, stream>>>(W1, W2, W1f, W2f);
  k_gemm1<<<NSC, 256, 0, stream>>>(x, W1f, B1, Aa, Bb, Ac, Bc);
  k_scan <<<NMAC, 256, 0, stream>>>(Ac, Bc, MtA, MtB);
  k_apply<<<NSC, 256, 0, stream>>>(Aa, Bb, Ac, Bc, MtA, MtB, W2f, B2, out);
}